// Round 12
// baseline (403.019 us; speedup 1.0000x reference)
//
#include <hip/hip_runtime.h>

typedef unsigned short u16;
typedef unsigned int   u32;
typedef __bf16  bf16x8 __attribute__((ext_vector_type(8)));
typedef float   f32x4  __attribute__((ext_vector_type(4)));

#define SEQ    2048
#define HEADS  16
#define DM     1024
#define NBH    32      /* B*H */
#define NBS    4096    /* B*S */

__device__ __forceinline__ u16 f2b(float f) {
    u32 x;
    __builtin_memcpy(&x, &f, 4);
    return (u16)((x + 0x7fffu + ((x >> 16) & 1u)) >> 16);  // RNE
}

__device__ __forceinline__ bf16x8 ld_bf8(const u16* p) {
    return *(const bf16x8*)p;
}
__device__ __forceinline__ bf16x8 ld_f32x8_cvt(const float* p) {
    f32x4 a = *(const f32x4*)p;
    f32x4 b = *(const f32x4*)(p + 4);
    bf16x8 r;
    r[0] = (__bf16)a[0]; r[1] = (__bf16)a[1]; r[2] = (__bf16)a[2]; r[3] = (__bf16)a[3];
    r[4] = (__bf16)b[0]; r[5] = (__bf16)b[1]; r[6] = (__bf16)b[2]; r[7] = (__bf16)b[3];
    return r;
}

// ---------------------------------------------------------------------------
// Transpose + fp32->bf16 of W_Q/W_K/W_V: (k,n) -> WqkvT[z*1024 + n][k].
// ---------------------------------------------------------------------------
__global__ __launch_bounds__(256) void transpose_wqkv(const float* __restrict__ Wq,
                                                      const float* __restrict__ Wk,
                                                      const float* __restrict__ Wv,
                                                      u16* __restrict__ WqkvT) {
    __shared__ u16 tile[64][65];
    const int z  = blockIdx.z;
    const float* src = (z == 0) ? Wq : (z == 1) ? Wk : Wv;
    const int k0 = blockIdx.x * 64, n0 = blockIdx.y * 64;
    const int tid = threadIdx.x;
    for (int i = 0; i < 16; ++i) {
        int e = i * 256 + tid;
        int r = e >> 6, c = e & 63;
        tile[r][c] = f2b(src[(size_t)(k0 + r) * DM + n0 + c]);
    }
    __syncthreads();
    u16* dst = WqkvT + (size_t)z * DM * DM;
    for (int i = 0; i < 16; ++i) {
        int e = i * 256 + tid;
        int r = e >> 6, c = e & 63;
        dst[(size_t)(n0 + r) * DM + k0 + c] = tile[c][r];
    }
}

// W_O (k,n) fp32 -> WoT[n][k] bf16. Launched AFTER flash (overlays dead vt).
__global__ __launch_bounds__(256) void transpose_wo(const float* __restrict__ Wo,
                                                    u16* __restrict__ WoT) {
    __shared__ u16 tile[64][65];
    const int k0 = blockIdx.x * 64, n0 = blockIdx.y * 64;
    const int tid = threadIdx.x;
    for (int i = 0; i < 16; ++i) {
        int e = i * 256 + tid;
        int r = e >> 6, c = e & 63;
        tile[r][c] = f2b(Wo[(size_t)(k0 + r) * DM + n0 + c]);
    }
    __syncthreads();
    for (int i = 0; i < 16; ++i) {
        int e = i * 256 + tid;
        int r = e >> 6, c = e & 63;
        WoT[(size_t)(n0 + r) * DM + k0 + c] = tile[c][r];
    }
}

// ---------------------------------------------------------------------------
// Shared GEMM body: 128x128 tile, BK=64, VGPR-mediated staging,
// 4 waves 2x2, 4x4 16x16x32 MFMA tiles per wave. acc[][] left for epilogue.
// ---------------------------------------------------------------------------
#define GEMM_BODY(A_EXPR, B_EXPR, K)                                                \
    __shared__ __attribute__((aligned(16))) __bf16 As[128 * 64];                    \
    __shared__ __attribute__((aligned(16))) __bf16 Bs[128 * 64];                    \
    const int tid  = threadIdx.x;                                                   \
    const int wave = tid >> 6, lane = tid & 63;                                     \
    const int quad = lane >> 4, col = lane & 15;                                    \
    const int wm = wave >> 1, wn = wave & 1;                                        \
    const int m0 = blockIdx.x * 128, n0 = blockIdx.y * 128;                         \
    const int srow = tid >> 3;            /* 0..31 */                               \
    const int scol = (tid & 7) * 8;       /* 0..56 */                               \
    f32x4 zero = {0.f, 0.f, 0.f, 0.f};                                              \
    f32x4 acc[4][4];                                                                \
    for (int i = 0; i < 4; ++i)                                                     \
        for (int j = 0; j < 4; ++j) acc[i][j] = zero;                               \
    for (int k0 = 0; k0 < (K); k0 += 64) {                                          \
        bf16x8 av[4], bv[4];                                                        \
        for (int p = 0; p < 4; ++p) {                                               \
            int row = p * 32 + srow;                                                \
            av[p] = A_EXPR;                                                         \
            bv[p] = B_EXPR;                                                         \
        }                                                                           \
        __syncthreads();                                                            \
        for (int p = 0; p < 4; ++p) {                                               \
            int row = p * 32 + srow;                                                \
            *(bf16x8*)&As[row * 64 + scol] = av[p];                                 \
            *(bf16x8*)&Bs[row * 64 + scol] = bv[p];                                 \
        }                                                                           \
        __syncthreads();                                                            \
        for (int ks = 0; ks < 2; ++ks) {                                            \
            bf16x8 af[4], bfr[4];                                                   \
            for (int mt = 0; mt < 4; ++mt)                                          \
                af[mt] = *(const bf16x8*)&As[(wm * 64 + mt * 16 + col) * 64 +       \
                                             ks * 32 + quad * 8];                   \
            for (int nt = 0; nt < 4; ++nt)                                          \
                bfr[nt] = *(const bf16x8*)&Bs[(wn * 64 + nt * 16 + col) * 64 +      \
                                              ks * 32 + quad * 8];                  \
            for (int mt = 0; mt < 4; ++mt)                                          \
                for (int nt = 0; nt < 4; ++nt)                                      \
                    acc[mt][nt] = __builtin_amdgcn_mfma_f32_16x16x32_bf16(          \
                        af[mt], bfr[nt], acc[mt][nt], 0, 0, 0);                     \
        }                                                                           \
    }

// ---------------------------------------------------------------------------
// Fused QKV GEMM: x(4096x1024 fp32) x WqkvT(3072x1024 bf16)^T.
// Epilogue scatters to Qp (bh,s,d), Kp (bh,s,d), Vt (bh,d,s).
// ---------------------------------------------------------------------------
__global__ __launch_bounds__(256) void gemm_qkv(const float* __restrict__ Af,
                                                const u16* __restrict__ Bt,
                                                u16* __restrict__ Qp,
                                                u16* __restrict__ Kp,
                                                u16* __restrict__ Vt) {
    GEMM_BODY(ld_f32x8_cvt(Af + (size_t)(m0 + row) * DM + k0 + scol),
              ld_bf8(Bt + (size_t)(n0 + row) * DM + k0 + scol), DM)
    // C/D: col = lane&15, row = quad*4 + reg (m89-verified).
    for (int mt = 0; mt < 4; ++mt)
        for (int nt = 0; nt < 4; ++nt) {
            int cc = n0 + wn * 64 + nt * 16 + col;       // [0,3072)
            int which = cc >> 10;                        // 0=Q 1=K 2=V
            int c1 = cc & 1023;
            int h = c1 >> 6, d = c1 & 63;
            for (int r = 0; r < 4; ++r) {
                int row = m0 + wm * 64 + mt * 16 + quad * 4 + r;   // [0,4096)
                int b = row >> 11, s = row & (SEQ - 1);
                u16 val = f2b(acc[mt][nt][r]);
                size_t bh = (size_t)(b * HEADS + h);
                if (which == 0)
                    Qp[(bh * SEQ + s) * 64 + d] = val;
                else if (which == 1)
                    Kp[(bh * SEQ + s) * 64 + d] = val;
                else
                    Vt[(bh * 64 + d) * SEQ + s] = val;
            }
        }
}

// ---------------------------------------------------------------------------
// Output GEMM: ao(4096x1024 bf16) x WoT(1024x1024 bf16)^T -> out FP32.
// ---------------------------------------------------------------------------
__global__ __launch_bounds__(256) void gemm_wo(const u16* __restrict__ A,
                                               const u16* __restrict__ Bt,
                                               float* __restrict__ C) {
    GEMM_BODY(ld_bf8(A + (size_t)(m0 + row) * DM + k0 + scol),
              ld_bf8(Bt + (size_t)(n0 + row) * DM + k0 + scol), DM)
    for (int mt = 0; mt < 4; ++mt)
        for (int nt = 0; nt < 4; ++nt)
            for (int r = 0; r < 4; ++r) {
                int row = m0 + wm * 64 + mt * 16 + quad * 4 + r;
                int cc  = n0 + wn * 64 + nt * 16 + col;
                C[(size_t)row * DM + cc] = acc[mt][nt][r];
            }
}

// ---------------------------------------------------------------------------
// RoPE for Q,K in-place on (bh,s,d) bf16; cos/sin fp32 (S x 32).
// token_positions == arange(SEQ). 8192 blocks x 256.
// ---------------------------------------------------------------------------
__global__ __launch_bounds__(256) void rope_qk(u16* __restrict__ Qp,
                                               u16* __restrict__ Kp,
                                               const float* __restrict__ cosT,
                                               const float* __restrict__ sinT) {
    int t = blockIdx.x * 256 + threadIdx.x;         // [0, 2^21)
    int p  = t & 31;
    int s  = (t >> 5) & (SEQ - 1);
    int hh = (t >> 16) & (HEADS - 1);
    int b  = t >> 20;

    float cv = cosT[s * 32 + p];
    float sv = sinT[s * 32 + p];

    size_t addr = (((size_t)(b * HEADS + hh)) * SEQ + s) * 64 + 2 * p;
    u32 q2 = *(const u32*)(Qp + addr);
    u32 k2 = *(const u32*)(Kp + addr);
    u32 qe_b = (q2 & 0xffff) << 16, qo_b = q2 & 0xffff0000u;
    u32 ke_b = (k2 & 0xffff) << 16, ko_b = k2 & 0xffff0000u;
    float qe, qo, ke, ko;
    __builtin_memcpy(&qe, &qe_b, 4); __builtin_memcpy(&qo, &qo_b, 4);
    __builtin_memcpy(&ke, &ke_b, 4); __builtin_memcpy(&ko, &ko_b, 4);

    u32 qout = (u32)f2b(cv * qe - sv * qo) | ((u32)f2b(sv * qe + cv * qo) << 16);
    u32 kout = (u32)f2b(cv * ke - sv * ko) | ((u32)f2b(sv * ke + cv * ko) << 16);
    *(u32*)(Qp + addr) = qout;
    *(u32*)(Kp + addr) = kout;
}

// ---------------------------------------------------------------------------
// Causal flash attention, UNPAIRED (R12): one 16-query tile per wave,
// grid (32, 32) heavy-first -> 4096 waves (2x R11) for latency hiding.
// Transposed scores S^T = K Q^T (per-lane softmax, R11-verified layout).
// P staging LDS stride padded 32->40: store bank = (20c+2q+r/2)%32 -> 2-way
// (free, m136); b128 read also 2-way. Kills R11's 8M conflict cycles.
// Qp,Kp: (bh, s, 64)  Vt: (bh, 64, s)  O: (b, s, h*64+d)  bf16
// ---------------------------------------------------------------------------
__global__ __launch_bounds__(256) void flash_attn(const u16* __restrict__ Qp,
                                                  const u16* __restrict__ Kp,
                                                  const u16* __restrict__ Vt,
                                                  u16* __restrict__ O) {
    __shared__ __bf16 Plds[4][16][40];      // [wave][query][key(+pad)]
    const int tid  = threadIdx.x;
    const int wave = tid >> 6, lane = tid & 63;
    const int quad = lane >> 4, col = lane & 15;
    const int bh = blockIdx.y;
    const int b = bh >> 4, h = bh & 15;
    const int q0 = (31 - blockIdx.x) * 64 + wave * 16;   // heavy blocks first

    const u16* Qb = Qp + (size_t)bh * SEQ * 64;
    const u16* Kb = Kp + (size_t)bh * SEQ * 64;
    const u16* Vb = Vt + (size_t)bh * 64 * SEQ;

    // Q as B-operand (n=lane&15 -> query, k=quad*8+j), two K-steps for dk=64
    bf16x8 bq0 = ld_bf8(Qb + (size_t)(q0 + col) * 64 + quad * 8);
    bf16x8 bq1 = ld_bf8(Qb + (size_t)(q0 + col) * 64 + 32 + quad * 8);

    f32x4 zero = {0.f, 0.f, 0.f, 0.f};
    f32x4 o[4];
    float m_i = -1e30f, l_i = 0.f;           // per-lane state for query q0+col
    for (int nt = 0; nt < 4; ++nt) o[nt] = zero;

    const int ntiles = (q0 + 47) >> 5;       // ceil((q0+16)/32); kb_last <= q0
    for (int kt = 0; kt < ntiles; ++kt) {
        const int kb = kt << 5;
        // ---- K as A-operand (m=lane&15 -> key)
        bf16x8 ak00 = ld_bf8(Kb + (size_t)(kb + col) * 64 + quad * 8);
        bf16x8 ak01 = ld_bf8(Kb + (size_t)(kb + col) * 64 + 32 + quad * 8);
        bf16x8 ak10 = ld_bf8(Kb + (size_t)(kb + 16 + col) * 64 + quad * 8);
        bf16x8 ak11 = ld_bf8(Kb + (size_t)(kb + 16 + col) * 64 + 32 + quad * 8);

        // S^T tiles: st[t][r] = score(key = kb + t*16 + quad*4 + r, query=col)
        f32x4 st0 = zero, st1 = zero;
        st0 = __builtin_amdgcn_mfma_f32_16x16x32_bf16(ak00, bq0, st0, 0, 0, 0);
        st0 = __builtin_amdgcn_mfma_f32_16x16x32_bf16(ak01, bq1, st0, 0, 0, 0);
        st1 = __builtin_amdgcn_mfma_f32_16x16x32_bf16(ak10, bq0, st1, 0, 0, 0);
        st1 = __builtin_amdgcn_mfma_f32_16x16x32_bf16(ak11, bq1, st1, 0, 0, 0);

        const int qrow = q0 + col;
        float v0[4], v1[4];
        float lm = -1e30f;
        for (int r = 0; r < 4; ++r) {
            int key0 = kb + quad * 4 + r;
            float a = st0[r] * 0.125f;
            float c = st1[r] * 0.125f;
            if (key0 > qrow)      a = -1e30f;
            if (key0 + 16 > qrow) c = -1e30f;
            v0[r] = a; v1[r] = c;
            lm = fmaxf(lm, fmaxf(a, c));
        }
        lm = fmaxf(lm, __shfl_xor(lm, 16));
        lm = fmaxf(lm, __shfl_xor(lm, 32));

        float mnew  = fmaxf(m_i, lm);
        float alpha = __expf(m_i - mnew);
        m_i = mnew;
        float ls = 0.f;
        for (int r = 0; r < 4; ++r) {
            v0[r] = __expf(v0[r] - mnew);
            v1[r] = __expf(v1[r] - mnew);
            ls += v0[r] + v1[r];
        }
        ls += __shfl_xor(ls, 16);
        ls += __shfl_xor(ls, 32);
        l_i = l_i * alpha + ls;

        // rescale o (rows = query quad*4+r): broadcast alpha from lane q
        for (int r = 0; r < 4; ++r) {
            float ar = __shfl(alpha, quad * 4 + r);
            for (int nt = 0; nt < 4; ++nt) o[nt][r] *= ar;
        }

        // P^T -> LDS in PV A-layout: Plds[q][key], padded stride
        for (int r = 0; r < 4; ++r) {
            Plds[wave][col][quad * 4 + r]      = (__bf16)v0[r];
            Plds[wave][col][16 + quad * 4 + r] = (__bf16)v1[r];
        }
        bf16x8 pf;
        for (int j = 0; j < 8; ++j)
            pf[j] = Plds[wave][col][quad * 8 + j];

        // ---- O += P V  (B-frag from Vt: contiguous 16B per lane)
        for (int nt = 0; nt < 4; ++nt) {
            bf16x8 bv = ld_bf8(Vb + (size_t)(nt * 16 + col) * SEQ + kb + quad * 8);
            o[nt] = __builtin_amdgcn_mfma_f32_16x16x32_bf16(pf, bv, o[nt], 0, 0, 0);
        }
    }

    float linv = 1.f / l_i;
    for (int r = 0; r < 4; ++r) {
        float lr = __shfl(linv, quad * 4 + r);
        int qrow = q0 + quad * 4 + r;
        for (int nt = 0; nt < 4; ++nt)
            O[((size_t)b * SEQ + qrow) * DM + h * 64 + nt * 16 + col] =
                f2b(o[nt][r] * lr);
    }
}

// ---------------------------------------------------------------------------
extern "C" void kernel_launch(void* const* d_in, const int* in_sizes, int n_in,
                              void* d_out, int out_size, void* d_ws, size_t ws_size,
                              hipStream_t stream) {
    const float* x    = (const float*)d_in[0];   // fp32 inputs (R3->R5 proven)
    const float* Wq   = (const float*)d_in[2];
    const float* Wk   = (const float*)d_in[3];
    const float* Wv   = (const float*)d_in[4];
    const float* Wo   = (const float*)d_in[5];
    const float* cosT = (const float*)d_in[6];
    const float* sinT = (const float*)d_in[7];
    float* out = (float*)d_out;                  // fp32 output (R8 proven)

    // Workspace: 16,777,216 u16 = 32 MiB (R8-proven safe size).
    u16* ws    = (u16*)d_ws;
    u16* qp    = ws;               // (bh,s,d)
    u16* kp    = ws + 4194304;
    u16* vt    = ws + 8388608;     // (bh,d,s); dead after flash
    u16* woT   = ws + 8388608;     // overlays vt, written after flash
    u16* wqkvT = ws + 12582912;    // dead after gemm_qkv
    u16* ao    = ws + 12582912;    // overlays wqkvT

    dim3 blk(256);
    transpose_wqkv<<<dim3(16, 16, 3), blk, 0, stream>>>(Wq, Wk, Wv, wqkvT);
    gemm_qkv<<<dim3(32, 24), blk, 0, stream>>>(x, wqkvT, qp, kp, vt);
    rope_qk<<<dim3(8192), blk, 0, stream>>>(qp, kp, cosT, sinT);
    flash_attn<<<dim3(32, NBH), blk, 0, stream>>>(qp, kp, vt, ao);
    transpose_wo<<<dim3(16, 16), blk, 0, stream>>>(Wo, woT);
    gemm_wo<<<dim3(32, 8), blk, 0, stream>>>(ao, woT, out);
}